// Round 1
// baseline (545.962 us; speedup 1.0000x reference)
//
#include <hip/hip_runtime.h>
#include <cstdint>
#include <cstddef>

typedef unsigned short u16;
typedef __attribute__((ext_vector_type(4))) float  float4v;
typedef __attribute__((ext_vector_type(4))) int    int4v;
typedef __attribute__((ext_vector_type(8))) short  short8v;
typedef __attribute__((ext_vector_type(4))) short  short4v;

#define L_SEQ 4096
#define NH 16
#define NKV 4

static __device__ __forceinline__ u16 f2bf(float f) {
  union { float f; unsigned u; } v; v.f = f;
  unsigned r = (v.u + 0x7FFFu + ((v.u >> 16) & 1u)) >> 16;  // RNE
  return (u16)r;
}

// ---------------- fp32 -> bf16 elementwise (x4 vectorized) ----------------
__global__ __launch_bounds__(256) void k_cvt(const float* __restrict__ in,
                                             u16* __restrict__ out, int n4) {
  int i = blockIdx.x * 256 + threadIdx.x;
  if (i >= n4) return;
  float4v v = ((const float4v*)in)[i];
  short4v o;
  o[0] = (short)f2bf(v[0]); o[1] = (short)f2bf(v[1]);
  o[2] = (short)f2bf(v[2]); o[3] = (short)f2bf(v[3]);
  ((short4v*)out)[i] = o;
}

// ------- transpose+convert: in fp32 [K][N] -> out bf16 [(row_off+n)][K] -------
__global__ __launch_bounds__(256) void k_transpose(const float* __restrict__ in,
                                                   u16* __restrict__ out,
                                                   int K, int N, int row_off) {
  __shared__ float tile[32][33];
  int n0 = blockIdx.x * 32, k0 = blockIdx.y * 32;
  int tx = threadIdx.x, ty = threadIdx.y;
#pragma unroll
  for (int i = 0; i < 4; i++)
    tile[ty + i*8][tx] = in[(size_t)(k0 + ty + i*8)*N + n0 + tx];
  __syncthreads();
#pragma unroll
  for (int i = 0; i < 4; i++)
    out[(size_t)(row_off + n0 + ty + i*8)*K + k0 + tx] = f2bf(tile[tx][ty + i*8]);
}

// ---------------- bf16 MFMA GEMM, B^T layout ----------------
// A: bf16 [M][K] row-major. B: bf16 [N][K] row-major. C: fp32 [M][N].
// 128x128 tile, BK=32, 4 waves (2x2), each wave 4x4 of 16x16x32 MFMA.
__global__ __launch_bounds__(256) void k_gemm_bt(const u16* __restrict__ A,
                                                 const u16* __restrict__ B,
                                                 float* __restrict__ C,
                                                 int M, int N, int K) {
  __shared__ alignas(16) u16 As[128*40];  // pad 32->40 (80B rows: 16B aligned, conflict-light)
  __shared__ alignas(16) u16 Bs[128*40];
  int tid = threadIdx.x;
  int lane = tid & 63, wave = tid >> 6;
  int lr = lane & 15, lg = lane >> 4;
  int m0 = blockIdx.y * 128, n0 = blockIdx.x * 128;
  int wm = (wave >> 1) * 64, wn = (wave & 1) * 64;

  float4v acc[4][4];
#pragma unroll
  for (int i = 0; i < 4; i++)
#pragma unroll
    for (int j = 0; j < 4; j++)
#pragma unroll
      for (int r = 0; r < 4; r++) acc[i][j][r] = 0.f;

  int r0 = tid >> 2;            // staging row (0..63), +64 on second pass
  int c0 = (tid & 3) << 3;      // staging col (0,8,16,24)

  for (int kt = 0; kt < K; kt += 32) {
    __syncthreads();
#pragma unroll
    for (int it = 0; it < 2; it++) {
      int row = r0 + it*64;
      *(int4v*)(&As[row*40 + c0]) = *(const int4v*)(A + (size_t)(m0 + row)*K + kt + c0);
      *(int4v*)(&Bs[row*40 + c0]) = *(const int4v*)(B + (size_t)(n0 + row)*K + kt + c0);
    }
    __syncthreads();
    short8v af[4], bf[4];
#pragma unroll
    for (int i = 0; i < 4; i++) af[i] = *(const short8v*)(&As[(wm + i*16 + lr)*40 + lg*8]);
#pragma unroll
    for (int j = 0; j < 4; j++) bf[j] = *(const short8v*)(&Bs[(wn + j*16 + lr)*40 + lg*8]);
#pragma unroll
    for (int i = 0; i < 4; i++)
#pragma unroll
      for (int j = 0; j < 4; j++)
        acc[i][j] = __builtin_amdgcn_mfma_f32_16x16x32_bf16(af[i], bf[j], acc[i][j], 0, 0, 0);
  }
  // C/D layout: row=(lane>>4)*4+reg, col=lane&15  [verified m89/m91]
#pragma unroll
  for (int i = 0; i < 4; i++)
#pragma unroll
    for (int j = 0; j < 4; j++)
#pragma unroll
      for (int r = 0; r < 4; r++)
        C[(size_t)(m0 + wm + i*16 + lg*4 + r)*N + (n0 + wn + j*16 + lr)] = acc[i][j][r];
}

// ---------------- RMSNorm + RoPE + layout shuffle ----------------
// qkv fp32 [L][3072] (q 0..2047 | k 2048..2559 | v 2560..3071)
// -> qb bf16 [L][16][128] (pre-scaled by HD^-0.5), kb bf16 [L][4][128],
//    vT bf16 [4][128][L]
__global__ __launch_bounds__(64) void k_qkv_post(const float* __restrict__ qkv,
    const int* __restrict__ positions, const float* __restrict__ q_scale,
    const float* __restrict__ k_scale, u16* __restrict__ qb,
    u16* __restrict__ kb, u16* __restrict__ vT) {
  int p = blockIdx.x;
  int idx = blockIdx.y;   // 0..15 q heads, 16..19 k heads, 20..23 v heads
  int l = threadIdx.x;    // 0..63: handles dims (l, l+64) = RoPE pair
  const float LOG2_BASE = 13.287712379549449f;  // log2(10000)
  if (idx < 16) {
    const float* src = qkv + (size_t)p*3072 + idx*128;
    float x1 = src[l], x2 = src[l + 64];
    float ss = x1*x1 + x2*x2;
#pragma unroll
    for (int m = 1; m < 64; m <<= 1) ss += __shfl_xor(ss, m);
    float rinv = rsqrtf(ss * (1.0f/128.0f) + 1e-6f);
    x1 *= rinv * q_scale[l];
    x2 *= rinv * q_scale[l + 64];
    float ang = (float)positions[p] * exp2f(-(float)l * (LOG2_BASE / 64.0f));
    float sn, cs; sincosf(ang, &sn, &cs);
    const float qsc = 0.08838834764831845f;  // 128^-0.5 pre-applied to Q
    u16* dst = qb + ((size_t)p*NH + idx)*128;
    dst[l]      = f2bf((x1*cs - x2*sn) * qsc);
    dst[l + 64] = f2bf((x2*cs + x1*sn) * qsc);
  } else if (idx < 20) {
    int g = idx - 16;
    const float* src = qkv + (size_t)p*3072 + 2048 + g*128;
    float x1 = src[l], x2 = src[l + 64];
    float ss = x1*x1 + x2*x2;
#pragma unroll
    for (int m = 1; m < 64; m <<= 1) ss += __shfl_xor(ss, m);
    float rinv = rsqrtf(ss * (1.0f/128.0f) + 1e-6f);
    x1 *= rinv * k_scale[l];
    x2 *= rinv * k_scale[l + 64];
    float ang = (float)positions[p] * exp2f(-(float)l * (LOG2_BASE / 64.0f));
    float sn, cs; sincosf(ang, &sn, &cs);
    u16* dst = kb + ((size_t)p*NKV + g)*128;
    dst[l]      = f2bf(x1*cs - x2*sn);
    dst[l + 64] = f2bf(x2*cs + x1*sn);
  } else {
    int g = idx - 20;
    const float* src = qkv + (size_t)p*3072 + 2560 + g*128;
    vT[((size_t)(g*128 + l     ))*L_SEQ + p] = f2bf(src[l]);
    vT[((size_t)(g*128 + l + 64))*L_SEQ + p] = f2bf(src[l + 64]);
  }
}

// ---------------- flash attention, MFMA, sliding window ----------------
// 1 wave per (head, 16-query tile). Key tiles of 32. Online softmax.
__global__ __launch_bounds__(64) void k_attn(const u16* __restrict__ qb,
    const u16* __restrict__ kb, const u16* __restrict__ vT,
    u16* __restrict__ ob) {
  __shared__ alignas(16) u16 P[16*32];  // P round-trip: C-layout -> A-layout
  int h = blockIdx.y;
  int q0 = blockIdx.x * 16;
  int gh = h >> 2;               // GQA: head h uses kv group h/4
  int lane = threadIdx.x;
  int lr = lane & 15, lg = lane >> 4;
  const float LOG2E = 1.44269504088896f;

  // Q A-fragments: A[m=lane&15][k=quad*8+j], 4 chunks cover HD=128
  short8v qf[4];
  const u16* qrow = qb + ((size_t)(q0 + lr)*NH + h)*128 + lg*8;
#pragma unroll
  for (int t = 0; t < 4; t++) qf[t] = *(const short8v*)(qrow + t*32);

  float4v O[8];
#pragma unroll
  for (int dt = 0; dt < 8; dt++)
#pragma unroll
    for (int r = 0; r < 4; r++) O[dt][r] = 0.f;
  float mprev[4] = {-3e38f, -3e38f, -3e38f, -3e38f};
  float lsum[4]  = {0.f, 0.f, 0.f, 0.f};

  int kstart = q0 - 1023; if (kstart < 0) kstart = 0; kstart &= ~31;
  for (int kt = kstart; kt <= q0 + 15; kt += 32) {
    // S = Q K^T : two 16x16 col-tiles, 4 MFMA each over HD
    float4v S[2];
#pragma unroll
    for (int t2 = 0; t2 < 2; t2++) {
#pragma unroll
      for (int r = 0; r < 4; r++) S[t2][r] = 0.f;
      const u16* krow = kb + ((size_t)(kt + t2*16 + lr)*NKV + gh)*128 + lg*8;
#pragma unroll
      for (int t = 0; t < 4; t++) {
        short8v kf = *(const short8v*)(krow + t*32);
        S[t2] = __builtin_amdgcn_mfma_f32_16x16x32_bf16(qf[t], kf, S[t2], 0, 0, 0);
      }
    }
    float alpha[4];
#pragma unroll
    for (int r = 0; r < 4; r++) {
      int pos = q0 + lg*4 + r;
      int key0 = kt + lr;
      if (key0 > pos      || key0 < pos - 1023)      S[0][r] = -3e38f;
      if (key0 + 16 > pos || key0 + 16 < pos - 1023) S[1][r] = -3e38f;
      float v = fmaxf(S[0][r], S[1][r]);
      v = fmaxf(v, __shfl_xor(v, 1));
      v = fmaxf(v, __shfl_xor(v, 2));
      v = fmaxf(v, __shfl_xor(v, 4));
      v = fmaxf(v, __shfl_xor(v, 8));
      float mn = fmaxf(mprev[r], v);
      alpha[r] = exp2f((mprev[r] - mn) * LOG2E);  // -> 0 when mprev=-3e38, mn finite
      float p0 = exp2f((S[0][r] - mn) * LOG2E);
      float p1 = exp2f((S[1][r] - mn) * LOG2E);
      float rs = p0 + p1;
      rs += __shfl_xor(rs, 1);
      rs += __shfl_xor(rs, 2);
      rs += __shfl_xor(rs, 4);
      rs += __shfl_xor(rs, 8);
      lsum[r] = lsum[r]*alpha[r] + rs;
      mprev[r] = mn;
      S[0][r] = p0; S[1][r] = p1;  // reuse as P
    }
#pragma unroll
    for (int dt = 0; dt < 8; dt++)
#pragma unroll
      for (int r = 0; r < 4; r++) O[dt][r] *= alpha[r];
    // P: C-layout -> LDS [16 q][32 keys] -> A-fragment
    __syncthreads();
#pragma unroll
    for (int r = 0; r < 4; r++) {
      P[(lg*4 + r)*32 + lr]      = f2bf(S[0][r]);
      P[(lg*4 + r)*32 + 16 + lr] = f2bf(S[1][r]);
    }
    __syncthreads();
    short8v pf = *(const short8v*)(&P[lr*32 + lg*8]);
#pragma unroll
    for (int dt = 0; dt < 8; dt++) {
      // B-frag: V[k=key][n=dim] from vT[gh][dim][key] (contiguous in key)
      const u16* vrow = vT + ((size_t)(gh*128 + dt*16 + lr))*L_SEQ + kt + lg*8;
      short8v vf = *(const short8v*)(vrow);
      O[dt] = __builtin_amdgcn_mfma_f32_16x16x32_bf16(pf, vf, O[dt], 0, 0, 0);
    }
  }
#pragma unroll
  for (int dt = 0; dt < 8; dt++)
#pragma unroll
    for (int r = 0; r < 4; r++)
      ob[((size_t)(q0 + lg*4 + r)*NH + h)*128 + dt*16 + lr] = f2bf(O[dt][r] / lsum[r]);
}

extern "C" void kernel_launch(void* const* d_in, const int* in_sizes, int n_in,
                              void* d_out, int out_size, void* d_ws, size_t ws_size,
                              hipStream_t stream) {
  (void)in_sizes; (void)n_in; (void)out_size; (void)ws_size;
  const float* x        = (const float*)d_in[0];
  const int*   positions= (const int*)d_in[1];
  const float* Wq       = (const float*)d_in[2];
  const float* Wk       = (const float*)d_in[3];
  const float* Wv       = (const float*)d_in[4];
  const float* Wo       = (const float*)d_in[5];
  const float* q_scale  = (const float*)d_in[6];
  const float* k_scale  = (const float*)d_in[7];
  float* out = (float*)d_out;

  // workspace carve (~108 MB); ob aliases qkv (qkv dead after k_qkv_post)
  char* ws = (char*)d_ws;
  u16*   xb  = (u16*)ws;   ws += (size_t)4096*2048*2;   // x bf16
  u16*   Wt  = (u16*)ws;   ws += (size_t)3072*2048*2;   // [Wq|Wk|Wv]^T bf16 [3072][2048]
  u16*   Wot = (u16*)ws;   ws += (size_t)2048*2048*2;   // Wo^T bf16 [2048][2048]
  float* qkv = (float*)ws; ws += (size_t)4096*3072*4;   // fused qkv fp32
  u16*   qb  = (u16*)ws;   ws += (size_t)4096*2048*2;   // q roped bf16
  u16*   kb  = (u16*)ws;   ws += (size_t)4096*512*2;    // k roped bf16
  u16*   vT  = (u16*)ws;   ws += (size_t)4096*512*2;    // v^T bf16 [4][128][L]
  u16*   ob  = (u16*)qkv;                               // attn out bf16 (aliases qkv)

  k_cvt<<<8192, 256, 0, stream>>>(x, xb, 2097152);
  k_transpose<<<dim3(64,64), dim3(32,8), 0, stream>>>(Wq, Wt, 2048, 2048, 0);
  k_transpose<<<dim3(16,64), dim3(32,8), 0, stream>>>(Wk, Wt, 2048, 512, 2048);
  k_transpose<<<dim3(16,64), dim3(32,8), 0, stream>>>(Wv, Wt, 2048, 512, 2560);
  k_transpose<<<dim3(64,64), dim3(32,8), 0, stream>>>(Wo, Wot, 2048, 2048, 0);
  k_gemm_bt<<<dim3(24,32), 256, 0, stream>>>(xb, Wt, qkv, 4096, 3072, 2048);
  k_qkv_post<<<dim3(4096,24), 64, 0, stream>>>(qkv, positions, q_scale, k_scale, qb, kb, vT);
  k_attn<<<dim3(256,16), 64, 0, stream>>>(qb, kb, vT, ob);
  k_gemm_bt<<<dim3(16,32), 256, 0, stream>>>(ob, Wot, out, 4096, 2048, 2048);
}

// Round 2
// 371.911 us; speedup vs baseline: 1.4680x; 1.4680x over previous
//
#include <hip/hip_runtime.h>
#include <cstdint>
#include <cstddef>

typedef unsigned short u16;
typedef __attribute__((ext_vector_type(4))) float  float4v;
typedef __attribute__((ext_vector_type(4))) int    int4v;
typedef __attribute__((ext_vector_type(8))) short  short8v;
typedef __attribute__((ext_vector_type(4))) short  short4v;

#define L_SEQ 4096
#define NH 16
#define NKV 4
#define WND 1024

static __device__ __forceinline__ u16 f2bf(float f) {
  union { float f; unsigned u; } v; v.f = f;
  unsigned r = (v.u + 0x7FFFu + ((v.u >> 16) & 1u)) >> 16;  // RNE
  return (u16)r;
}

// ---------------- fp32 -> bf16 elementwise (x4 vectorized) ----------------
__global__ __launch_bounds__(256) void k_cvt(const float* __restrict__ in,
                                             u16* __restrict__ out, int n4) {
  int i = blockIdx.x * 256 + threadIdx.x;
  if (i >= n4) return;
  float4v v = ((const float4v*)in)[i];
  short4v o;
  o[0] = (short)f2bf(v[0]); o[1] = (short)f2bf(v[1]);
  o[2] = (short)f2bf(v[2]); o[3] = (short)f2bf(v[3]);
  ((short4v*)out)[i] = o;
}

// ------- transpose+convert: in fp32 [K][N] -> out bf16 [(row_off+n)][K] -------
__global__ __launch_bounds__(256) void k_transpose(const float* __restrict__ in,
                                                   u16* __restrict__ out,
                                                   int K, int N, int row_off) {
  __shared__ float tile[32][33];
  int n0 = blockIdx.x * 32, k0 = blockIdx.y * 32;
  int tx = threadIdx.x, ty = threadIdx.y;
#pragma unroll
  for (int i = 0; i < 4; i++)
    tile[ty + i*8][tx] = in[(size_t)(k0 + ty + i*8)*N + n0 + tx];
  __syncthreads();
#pragma unroll
  for (int i = 0; i < 4; i++)
    out[(size_t)(row_off + n0 + ty + i*8)*K + k0 + tx] = f2bf(tile[tx][ty + i*8]);
}

// ---------------- bf16 MFMA GEMM, B^T layout, m97 structure ----------------
// A: bf16 [M][K] row-major. B: bf16 [N][K] row-major. C: fp32 [M][N].
// 128x128 tile, BK=32, 4 waves (2x2), 4x4 MFMA/wave, global_load_lds width 16.
// LDS tiles UNPADDED (global_load_lds dest must be base + lane*16 — m104).
__global__ __launch_bounds__(256) void k_gemm_bt(const u16* __restrict__ A,
                                                 const u16* __restrict__ B,
                                                 float* __restrict__ C,
                                                 int M, int N, int K) {
  __shared__ alignas(16) u16 As[128*32];
  __shared__ alignas(16) u16 Bs[128*32];
  int tid = threadIdx.x;
  int lane = tid & 63, wave = tid >> 6;
  int lr = lane & 15, lg = lane >> 4;
  int m0 = blockIdx.y * 128, n0 = blockIdx.x * 128;
  int wm = (wave >> 1) * 64, wn = (wave & 1) * 64;

  float4v acc[4][4];
#pragma unroll
  for (int i = 0; i < 4; i++)
#pragma unroll
    for (int j = 0; j < 4; j++)
#pragma unroll
      for (int r = 0; r < 4; r++) acc[i][j][r] = 0.f;

  for (int kt = 0; kt < K; kt += 32) {
    __syncthreads();
#pragma unroll
    for (int it = 0; it < 2; it++) {
      int chunk = it * 256 + tid;           // 512 chunks of 8 bf16 (16B)
      int row = chunk >> 2, c = (chunk & 3) << 3;
      __builtin_amdgcn_global_load_lds(
          (const __attribute__((address_space(1))) void*)(A + (size_t)(m0 + row)*K + kt + c),
          (__attribute__((address_space(3))) void*)(&As[chunk * 8]), 16, 0, 0);
      __builtin_amdgcn_global_load_lds(
          (const __attribute__((address_space(1))) void*)(B + (size_t)(n0 + row)*K + kt + c),
          (__attribute__((address_space(3))) void*)(&Bs[chunk * 8]), 16, 0, 0);
    }
    __syncthreads();
    short8v af[4], bf[4];
#pragma unroll
    for (int i = 0; i < 4; i++) af[i] = *(const short8v*)(&As[(wm + i*16 + lr)*32 + lg*8]);
#pragma unroll
    for (int j = 0; j < 4; j++) bf[j] = *(const short8v*)(&Bs[(wn + j*16 + lr)*32 + lg*8]);
#pragma unroll
    for (int i = 0; i < 4; i++)
#pragma unroll
      for (int j = 0; j < 4; j++)
        acc[i][j] = __builtin_amdgcn_mfma_f32_16x16x32_bf16(af[i], bf[j], acc[i][j], 0, 0, 0);
  }
  // C/D layout: row=(lane>>4)*4+reg, col=lane&15  [verified m89/m91]
#pragma unroll
  for (int i = 0; i < 4; i++)
#pragma unroll
    for (int j = 0; j < 4; j++)
#pragma unroll
      for (int r = 0; r < 4; r++)
        C[(size_t)(m0 + wm + i*16 + lg*4 + r)*N + (n0 + wn + j*16 + lr)] = acc[i][j][r];
}

// ---------------- RMSNorm + RoPE + layout shuffle ----------------
__global__ __launch_bounds__(64) void k_qkv_post(const float* __restrict__ qkv,
    const int* __restrict__ positions, const float* __restrict__ q_scale,
    const float* __restrict__ k_scale, u16* __restrict__ qb,
    u16* __restrict__ kb, u16* __restrict__ vT) {
  int p = blockIdx.x;
  int idx = blockIdx.y;   // 0..15 q heads, 16..19 k heads, 20..23 v heads
  int l = threadIdx.x;    // dims (l, l+64) = RoPE pair
  const float LOG2_BASE = 13.287712379549449f;  // log2(10000)
  if (idx < 16) {
    const float* src = qkv + (size_t)p*3072 + idx*128;
    float x1 = src[l], x2 = src[l + 64];
    float ss = x1*x1 + x2*x2;
#pragma unroll
    for (int m = 1; m < 64; m <<= 1) ss += __shfl_xor(ss, m);
    float rinv = rsqrtf(ss * (1.0f/128.0f) + 1e-6f);
    x1 *= rinv * q_scale[l];
    x2 *= rinv * q_scale[l + 64];
    float ang = (float)positions[p] * exp2f(-(float)l * (LOG2_BASE / 64.0f));
    float sn, cs; sincosf(ang, &sn, &cs);
    const float qsc = 0.08838834764831845f;  // 128^-0.5 pre-applied to Q
    u16* dst = qb + ((size_t)p*NH + idx)*128;
    dst[l]      = f2bf((x1*cs - x2*sn) * qsc);
    dst[l + 64] = f2bf((x2*cs + x1*sn) * qsc);
  } else if (idx < 20) {
    int g = idx - 16;
    const float* src = qkv + (size_t)p*3072 + 2048 + g*128;
    float x1 = src[l], x2 = src[l + 64];
    float ss = x1*x1 + x2*x2;
#pragma unroll
    for (int m = 1; m < 64; m <<= 1) ss += __shfl_xor(ss, m);
    float rinv = rsqrtf(ss * (1.0f/128.0f) + 1e-6f);
    x1 *= rinv * k_scale[l];
    x2 *= rinv * k_scale[l + 64];
    float ang = (float)positions[p] * exp2f(-(float)l * (LOG2_BASE / 64.0f));
    float sn, cs; sincosf(ang, &sn, &cs);
    u16* dst = kb + ((size_t)p*NKV + g)*128;
    dst[l]      = f2bf(x1*cs - x2*sn);
    dst[l + 64] = f2bf(x2*cs + x1*sn);
  } else {
    int g = idx - 20;
    const float* src = qkv + (size_t)p*3072 + 2560 + g*128;
    vT[((size_t)(g*128 + l     ))*L_SEQ + p] = f2bf(src[l]);
    vT[((size_t)(g*128 + l + 64))*L_SEQ + p] = f2bf(src[l + 64]);
  }
}

// ---------------- flash attention v2: GQA-shared K/V, fixed-max softmax ----------------
// Block = 256 thr = 4 waves = the 4 heads of one kv group. 32 queries/block.
// K/V tiles (32 keys) staged in padded LDS once, shared by all 4 waves.
// Fixed-max softmax: |S| <= 128*HD^-0.5 ~ 11.3 (RMSNorm bound) -> exp2 safe in fp32;
// no running max, no O rescale; denominator lane-reduced once at the end.
__global__ __launch_bounds__(256) void k_attn(const u16* __restrict__ qb,
    const u16* __restrict__ kb, const u16* __restrict__ vT,
    u16* __restrict__ ob) {
  __shared__ alignas(16) u16 Ks[32*136];    // [key][dim], pad 128->136: 2-way banks
  __shared__ alignas(16) u16 Vs[128*40];    // [dim][key], pad 32->40
  __shared__ alignas(16) u16 Pw[4][2][16*40]; // per-wave P transpose, pad 32->40
  int tid = threadIdx.x;
  int lane = tid & 63, wave = tid >> 6;
  int lr = lane & 15, lg = lane >> 4;
  int gh = blockIdx.y;
  int h = gh * 4 + wave;
  int q0 = blockIdx.x * 32;
  const float LOG2E = 1.44269504088896f;

  // Q A-frags for two 16-query subtiles: A[m=lr][k=lg*8+j]
  short8v qf[2][4];
#pragma unroll
  for (int m = 0; m < 2; m++) {
    const u16* qrow = qb + ((size_t)(q0 + m*16 + lr)*NH + h)*128 + lg*8;
#pragma unroll
    for (int t = 0; t < 4; t++) qf[m][t] = *(const short8v*)(qrow + t*32);
  }

  float4v O[8][2];
#pragma unroll
  for (int dt = 0; dt < 8; dt++)
#pragma unroll
    for (int m = 0; m < 2; m++)
#pragma unroll
      for (int r = 0; r < 4; r++) O[dt][m][r] = 0.f;
  float lsum[2][4] = {{0.f,0.f,0.f,0.f},{0.f,0.f,0.f,0.f}};

  int kstart = q0 - (WND - 1); if (kstart < 0) kstart = 0; kstart &= ~31;
  for (int kt = kstart; kt < q0 + 32; kt += 32) {
    __syncthreads();   // protect LDS from previous iteration's readers
#pragma unroll
    for (int it = 0; it < 2; it++) {
      int c = it*256 + tid;
      { int row = c >> 4, cc = (c & 15) << 3;   // K: 32 rows x 16 chunks
        *(int4v*)(&Ks[row*136 + cc]) =
            *(const int4v*)(kb + ((size_t)(kt + row)*NKV + gh)*128 + cc); }
      { int row = c >> 2, cc = (c & 3) << 3;    // V: 128 rows x 4 chunks
        *(int4v*)(&Vs[row*40 + cc]) =
            *(const int4v*)(vT + (size_t)(gh*128 + row)*L_SEQ + kt + cc); }
    }
    __syncthreads();

    // S = Q K^T : [msub][key col-tile]
    float4v S[2][2];
#pragma unroll
    for (int m = 0; m < 2; m++)
#pragma unroll
      for (int t2 = 0; t2 < 2; t2++)
#pragma unroll
        for (int r = 0; r < 4; r++) S[m][t2][r] = 0.f;
#pragma unroll
    for (int t2 = 0; t2 < 2; t2++)
#pragma unroll
      for (int t = 0; t < 4; t++) {
        short8v kf = *(const short8v*)(&Ks[(t2*16 + lr)*136 + t*32 + lg*8]);
        S[0][t2] = __builtin_amdgcn_mfma_f32_16x16x32_bf16(qf[0][t], kf, S[0][t2], 0, 0, 0);
        S[1][t2] = __builtin_amdgcn_mfma_f32_16x16x32_bf16(qf[1][t], kf, S[1][t2], 0, 0, 0);
      }

    // mask + exp (fixed max) + partial denominators + P transpose via wave-private LDS
#pragma unroll
    for (int m = 0; m < 2; m++)
#pragma unroll
      for (int r = 0; r < 4; r++) {
        int pos = q0 + m*16 + lg*4 + r;
#pragma unroll
        for (int t2 = 0; t2 < 2; t2++) {
          int key = kt + t2*16 + lr;
          float p = (key > pos || key < pos - (WND - 1))
                      ? 0.f : exp2f(S[m][t2][r] * LOG2E);
          lsum[m][r] += p;
          Pw[wave][m][(lg*4 + r)*40 + t2*16 + lr] = f2bf(p);
        }
      }
    short8v pf[2];
#pragma unroll
    for (int m = 0; m < 2; m++)
      pf[m] = *(const short8v*)(&Pw[wave][m][lr*40 + lg*8]);  // wave-private: no barrier

#pragma unroll
    for (int dt = 0; dt < 8; dt++) {
      short8v vf = *(const short8v*)(&Vs[(dt*16 + lr)*40 + lg*8]);
      O[dt][0] = __builtin_amdgcn_mfma_f32_16x16x32_bf16(pf[0], vf, O[dt][0], 0, 0, 0);
      O[dt][1] = __builtin_amdgcn_mfma_f32_16x16x32_bf16(pf[1], vf, O[dt][1], 0, 0, 0);
    }
  }

#pragma unroll
  for (int m = 0; m < 2; m++)
#pragma unroll
    for (int r = 0; r < 4; r++) {
      float s = lsum[m][r];
      s += __shfl_xor(s, 1); s += __shfl_xor(s, 2);
      s += __shfl_xor(s, 4); s += __shfl_xor(s, 8);
      float inv = 1.0f / s;
#pragma unroll
      for (int dt = 0; dt < 8; dt++)
        ob[((size_t)(q0 + m*16 + lg*4 + r)*NH + h)*128 + dt*16 + lr] =
            f2bf(O[dt][m][r] * inv);
    }
}

extern "C" void kernel_launch(void* const* d_in, const int* in_sizes, int n_in,
                              void* d_out, int out_size, void* d_ws, size_t ws_size,
                              hipStream_t stream) {
  (void)in_sizes; (void)n_in; (void)out_size; (void)ws_size;
  const float* x        = (const float*)d_in[0];
  const int*   positions= (const int*)d_in[1];
  const float* Wq       = (const float*)d_in[2];
  const float* Wk       = (const float*)d_in[3];
  const float* Wv       = (const float*)d_in[4];
  const float* Wo       = (const float*)d_in[5];
  const float* q_scale  = (const float*)d_in[6];
  const float* k_scale  = (const float*)d_in[7];
  float* out = (float*)d_out;

  char* ws = (char*)d_ws;
  u16*   xb  = (u16*)ws;   ws += (size_t)4096*2048*2;   // x bf16
  u16*   Wt  = (u16*)ws;   ws += (size_t)3072*2048*2;   // [Wq|Wk|Wv]^T bf16
  u16*   Wot = (u16*)ws;   ws += (size_t)2048*2048*2;   // Wo^T bf16
  float* qkv = (float*)ws; ws += (size_t)4096*3072*4;   // fused qkv fp32
  u16*   qb  = (u16*)ws;   ws += (size_t)4096*2048*2;   // q roped bf16 (pre-scaled)
  u16*   kb  = (u16*)ws;   ws += (size_t)4096*512*2;    // k roped bf16
  u16*   vT  = (u16*)ws;   ws += (size_t)4096*512*2;    // v^T bf16 [4][128][L]
  u16*   ob  = (u16*)qkv;                               // attn out bf16 (aliases qkv)

  k_cvt<<<8192, 256, 0, stream>>>(x, xb, 2097152);
  k_transpose<<<dim3(64,64), dim3(32,8), 0, stream>>>(Wq, Wt, 2048, 2048, 0);
  k_transpose<<<dim3(16,64), dim3(32,8), 0, stream>>>(Wk, Wt, 2048, 512, 2048);
  k_transpose<<<dim3(16,64), dim3(32,8), 0, stream>>>(Wv, Wt, 2048, 512, 2560);
  k_transpose<<<dim3(64,64), dim3(32,8), 0, stream>>>(Wo, Wot, 2048, 2048, 0);
  k_gemm_bt<<<dim3(24,32), 256, 0, stream>>>(xb, Wt, qkv, 4096, 3072, 2048);
  k_qkv_post<<<dim3(4096,24), 64, 0, stream>>>(qkv, positions, q_scale, k_scale, qb, kb, vT);
  k_attn<<<dim3(128,4), 256, 0, stream>>>(qb, kb, vT, ob);
  k_gemm_bt<<<dim3(16,32), 256, 0, stream>>>(ob, Wot, out, 4096, 2048, 2048);
}

// Round 3
// 316.190 us; speedup vs baseline: 1.7267x; 1.1762x over previous
//
#include <hip/hip_runtime.h>
#include <cstdint>
#include <cstddef>

typedef unsigned short u16;
typedef __attribute__((ext_vector_type(4))) float  float4v;
typedef __attribute__((ext_vector_type(4))) int    int4v;
typedef __attribute__((ext_vector_type(8))) short  short8v;
typedef __attribute__((ext_vector_type(4))) short  short4v;

#define L_SEQ 4096
#define NH 16
#define NKV 4
#define WND 1024

static __device__ __forceinline__ u16 f2bf(float f) {
  union { float f; unsigned u; } v; v.f = f;
  unsigned r = (v.u + 0x7FFFu + ((v.u >> 16) & 1u)) >> 16;  // RNE
  return (u16)r;
}
static __device__ __forceinline__ float bf2f(u16 b) {
  union { unsigned u; float f; } v; v.u = ((unsigned)b) << 16;
  return v.f;
}

// ---------------- fp32 -> bf16 elementwise (x4 vectorized) ----------------
__global__ __launch_bounds__(256) void k_cvt(const float* __restrict__ in,
                                             u16* __restrict__ out, int n4) {
  int i = blockIdx.x * 256 + threadIdx.x;
  if (i >= n4) return;
  float4v v = ((const float4v*)in)[i];
  short4v o;
  o[0] = (short)f2bf(v[0]); o[1] = (short)f2bf(v[1]);
  o[2] = (short)f2bf(v[2]); o[3] = (short)f2bf(v[3]);
  ((short4v*)out)[i] = o;
}

// --- transpose+convert 64x64: in fp32 [K][N] -> out bf16 [(row_off+n)][K] ---
__global__ __launch_bounds__(256) void k_transpose64(const float* __restrict__ in,
                                                     u16* __restrict__ out,
                                                     int K, int N, int row_off) {
  __shared__ float tile[64][65];   // 65: stride%32==1 -> 2-way banks (free)
  int n0 = blockIdx.x * 64, k0 = blockIdx.y * 64;
  int tx = threadIdx.x & 63, ty = threadIdx.x >> 6;
#pragma unroll
  for (int i = 0; i < 16; i++)
    tile[ty + i*4][tx] = in[(size_t)(k0 + ty + i*4)*N + n0 + tx];
  __syncthreads();
#pragma unroll
  for (int i = 0; i < 16; i++)
    out[(size_t)(row_off + n0 + ty + i*4)*K + k0 + tx] = f2bf(tile[tx][ty + i*4]);
}

// --- V extract+transpose: qkvb bf16 [L][3072] cols 2560.. -> vT bf16 [512][L] ---
__global__ __launch_bounds__(256) void k_vtrans(const u16* __restrict__ qkvb,
                                                u16* __restrict__ vT) {
  __shared__ u16 tile[64][66];     // 66: stride/2 % 32 == 1 -> 2-way banks
  int p0 = blockIdx.x * 64, d0 = blockIdx.y * 64;
  int tx = threadIdx.x & 63, ty = threadIdx.x >> 6;
#pragma unroll
  for (int i = 0; i < 16; i++)
    tile[ty + i*4][tx] = qkvb[(size_t)(p0 + ty + i*4)*3072 + 2560 + d0 + tx];
  __syncthreads();
#pragma unroll
  for (int i = 0; i < 16; i++)
    vT[(size_t)(d0 + ty + i*4)*L_SEQ + p0 + tx] = tile[tx][ty + i*4];
}

// ---------------- bf16 MFMA GEMM, B^T, BK=64, XOR-swizzled LDS ----------------
// A: bf16 [M][K]. B: bf16 [N][K]. C: fp32 or bf16 [M][N].
// 128x128 tile, 4 waves (2x2), 4x4 MFMA/wave, global_load_lds width 16.
// LDS rows are 64 bf16 = 128 B; chunk c of row stored at slot c ^ (row&7):
// keeps DMA lane-contiguity AND gives 2-way (free) banks on ds_read_b128.
template<int BF16_OUT>
__global__ __launch_bounds__(256) void k_gemm_bt(const u16* __restrict__ A,
                                                 const u16* __restrict__ B,
                                                 void* __restrict__ Cv,
                                                 int M, int N, int K) {
  __shared__ alignas(16) u16 As[128*64];
  __shared__ alignas(16) u16 Bs[128*64];
  int tid = threadIdx.x;
  int lane = tid & 63, wave = tid >> 6;
  int lr = lane & 15, lg = lane >> 4;
  int m0 = blockIdx.y * 128, n0 = blockIdx.x * 128;
  int wm = (wave >> 1) * 64, wn = (wave & 1) * 64;

  float4v acc[4][4];
#pragma unroll
  for (int i = 0; i < 4; i++)
#pragma unroll
    for (int j = 0; j < 4; j++)
#pragma unroll
      for (int r = 0; r < 4; r++) acc[i][j][r] = 0.f;

  for (int kt = 0; kt < K; kt += 64) {
    __syncthreads();
#pragma unroll
    for (int it = 0; it < 4; it++) {
      int s = it*256 + tid;                 // 1024 chunks of 16 B per tile
      int row = s >> 3, j = s & 7;
      int col = ((j ^ (row & 7)) << 3);     // swizzled source column
      __builtin_amdgcn_global_load_lds(
          (const __attribute__((address_space(1))) void*)(A + (size_t)(m0 + row)*K + kt + col),
          (__attribute__((address_space(3))) void*)(&As[s * 8]), 16, 0, 0);
      __builtin_amdgcn_global_load_lds(
          (const __attribute__((address_space(1))) void*)(B + (size_t)(n0 + row)*K + kt + col),
          (__attribute__((address_space(3))) void*)(&Bs[s * 8]), 16, 0, 0);
    }
    __syncthreads();
#pragma unroll
    for (int half = 0; half < 2; half++) {
      short8v af[4], bf[4];
#pragma unroll
      for (int i = 0; i < 4; i++) {
        int row = wm + i*16 + lr;
        af[i] = *(const short8v*)(&As[row*64 + ((((half<<2)|lg) ^ (row & 7)) << 3)]);
      }
#pragma unroll
      for (int j = 0; j < 4; j++) {
        int row = wn + j*16 + lr;
        bf[j] = *(const short8v*)(&Bs[row*64 + ((((half<<2)|lg) ^ (row & 7)) << 3)]);
      }
#pragma unroll
      for (int i = 0; i < 4; i++)
#pragma unroll
        for (int j = 0; j < 4; j++)
          acc[i][j] = __builtin_amdgcn_mfma_f32_16x16x32_bf16(af[i], bf[j], acc[i][j], 0, 0, 0);
    }
  }
  // C/D layout: row=(lane>>4)*4+reg, col=lane&15  [verified m89/m91]
#pragma unroll
  for (int i = 0; i < 4; i++)
#pragma unroll
    for (int j = 0; j < 4; j++)
#pragma unroll
      for (int r = 0; r < 4; r++) {
        size_t idx = (size_t)(m0 + wm + i*16 + lg*4 + r)*N + (n0 + wn + j*16 + lr);
        if (BF16_OUT) ((u16*)Cv)[idx] = f2bf(acc[i][j][r]);
        else          ((float*)Cv)[idx] = acc[i][j][r];
      }
}

// ---------------- RMSNorm + RoPE for Q,K (sincos amortized over heads) ----------------
// qkvb bf16 [L][3072] -> qb bf16 [L][16][128] (pre-scaled HD^-0.5), kb bf16 [L][4][128]
__global__ __launch_bounds__(256) void k_qknorm(const u16* __restrict__ qkvb,
    const int* __restrict__ positions, const float* __restrict__ q_scale,
    const float* __restrict__ k_scale, u16* __restrict__ qb,
    u16* __restrict__ kb) {
  int p = blockIdx.x * 4 + (threadIdx.x >> 6);   // wave -> position
  int l = threadIdx.x & 63;                      // dims (l, l+64) = RoPE pair
  const float LOG2_BASE = 13.287712379549449f;   // log2(10000)
  float ang = (float)positions[p] * exp2f(-(float)l * (LOG2_BASE / 64.0f));
  float sn, cs; sincosf(ang, &sn, &cs);
  float qs1 = q_scale[l], qs2 = q_scale[l + 64];
  float ks1 = k_scale[l], ks2 = k_scale[l + 64];
  const u16* base = qkvb + (size_t)p * 3072;
  const float qsc = 0.08838834764831845f;        // 128^-0.5 pre-applied to Q
#pragma unroll
  for (int h = 0; h < 16; h++) {
    float x1 = bf2f(base[h*128 + l]), x2 = bf2f(base[h*128 + l + 64]);
    float ss = x1*x1 + x2*x2;
#pragma unroll
    for (int m = 1; m < 64; m <<= 1) ss += __shfl_xor(ss, m);
    float rinv = rsqrtf(ss * (1.0f/128.0f) + 1e-6f);
    x1 *= rinv * qs1; x2 *= rinv * qs2;
    u16* dst = qb + ((size_t)p*NH + h)*128;
    dst[l]      = f2bf((x1*cs - x2*sn) * qsc);
    dst[l + 64] = f2bf((x2*cs + x1*sn) * qsc);
  }
#pragma unroll
  for (int g = 0; g < 4; g++) {
    float x1 = bf2f(base[2048 + g*128 + l]), x2 = bf2f(base[2048 + g*128 + l + 64]);
    float ss = x1*x1 + x2*x2;
#pragma unroll
    for (int m = 1; m < 64; m <<= 1) ss += __shfl_xor(ss, m);
    float rinv = rsqrtf(ss * (1.0f/128.0f) + 1e-6f);
    x1 *= rinv * ks1; x2 *= rinv * ks2;
    u16* dst = kb + ((size_t)p*NKV + g)*128;
    dst[l]      = f2bf(x1*cs - x2*sn);
    dst[l + 64] = f2bf(x2*cs + x1*sn);
  }
}

// ---------------- flash attention: GQA-shared K/V, fixed-max softmax ----------------
// Block = 256 thr = 4 waves = the 4 heads of one kv group. 32 queries/block.
// Fixed-max softmax: RMSNorm bounds |S| <= 11.4 -> exp2 safe in fp32.
__global__ __launch_bounds__(256) void k_attn(const u16* __restrict__ qb,
    const u16* __restrict__ kb, const u16* __restrict__ vT,
    u16* __restrict__ ob) {
  __shared__ alignas(16) u16 Ks[32*136];      // [key][dim], pad 128->136
  __shared__ alignas(16) u16 Vs[128*40];      // [dim][key], pad 32->40
  __shared__ alignas(16) u16 Pw[4][2][16*40]; // per-wave P transpose
  int tid = threadIdx.x;
  int lane = tid & 63, wave = tid >> 6;
  int lr = lane & 15, lg = lane >> 4;
  int gh = blockIdx.y;
  int h = gh * 4 + wave;
  int q0 = blockIdx.x * 32;
  const float LOG2E = 1.44269504088896f;

  short8v qf[2][4];
#pragma unroll
  for (int m = 0; m < 2; m++) {
    const u16* qrow = qb + ((size_t)(q0 + m*16 + lr)*NH + h)*128 + lg*8;
#pragma unroll
    for (int t = 0; t < 4; t++) qf[m][t] = *(const short8v*)(qrow + t*32);
  }

  float4v O[8][2];
#pragma unroll
  for (int dt = 0; dt < 8; dt++)
#pragma unroll
    for (int m = 0; m < 2; m++)
#pragma unroll
      for (int r = 0; r < 4; r++) O[dt][m][r] = 0.f;
  float lsum[2][4] = {{0.f,0.f,0.f,0.f},{0.f,0.f,0.f,0.f}};

  int kstart = q0 - (WND - 1); if (kstart < 0) kstart = 0; kstart &= ~31;
  for (int kt = kstart; kt < q0 + 32; kt += 32) {
    __syncthreads();
#pragma unroll
    for (int it = 0; it < 2; it++) {
      int c = it*256 + tid;
      { int row = c >> 4, cc = (c & 15) << 3;
        *(int4v*)(&Ks[row*136 + cc]) =
            *(const int4v*)(kb + ((size_t)(kt + row)*NKV + gh)*128 + cc); }
      { int row = c >> 2, cc = (c & 3) << 3;
        *(int4v*)(&Vs[row*40 + cc]) =
            *(const int4v*)(vT + (size_t)(gh*128 + row)*L_SEQ + kt + cc); }
    }
    __syncthreads();

    float4v S[2][2];
#pragma unroll
    for (int m = 0; m < 2; m++)
#pragma unroll
      for (int t2 = 0; t2 < 2; t2++)
#pragma unroll
        for (int r = 0; r < 4; r++) S[m][t2][r] = 0.f;
#pragma unroll
    for (int t2 = 0; t2 < 2; t2++)
#pragma unroll
      for (int t = 0; t < 4; t++) {
        short8v kf = *(const short8v*)(&Ks[(t2*16 + lr)*136 + t*32 + lg*8]);
        S[0][t2] = __builtin_amdgcn_mfma_f32_16x16x32_bf16(qf[0][t], kf, S[0][t2], 0, 0, 0);
        S[1][t2] = __builtin_amdgcn_mfma_f32_16x16x32_bf16(qf[1][t], kf, S[1][t2], 0, 0, 0);
      }

#pragma unroll
    for (int m = 0; m < 2; m++)
#pragma unroll
      for (int r = 0; r < 4; r++) {
        int pos = q0 + m*16 + lg*4 + r;
#pragma unroll
        for (int t2 = 0; t2 < 2; t2++) {
          int key = kt + t2*16 + lr;
          float p = (key > pos || key < pos - (WND - 1))
                      ? 0.f : exp2f(S[m][t2][r] * LOG2E);
          lsum[m][r] += p;
          Pw[wave][m][(lg*4 + r)*40 + t2*16 + lr] = f2bf(p);
        }
      }
    short8v pf[2];
#pragma unroll
    for (int m = 0; m < 2; m++)
      pf[m] = *(const short8v*)(&Pw[wave][m][lr*40 + lg*8]);

#pragma unroll
    for (int dt = 0; dt < 8; dt++) {
      short8v vf = *(const short8v*)(&Vs[(dt*16 + lr)*40 + lg*8]);
      O[dt][0] = __builtin_amdgcn_mfma_f32_16x16x32_bf16(pf[0], vf, O[dt][0], 0, 0, 0);
      O[dt][1] = __builtin_amdgcn_mfma_f32_16x16x32_bf16(pf[1], vf, O[dt][1], 0, 0, 0);
    }
  }

#pragma unroll
  for (int m = 0; m < 2; m++)
#pragma unroll
    for (int r = 0; r < 4; r++) {
      float s = lsum[m][r];
      s += __shfl_xor(s, 1); s += __shfl_xor(s, 2);
      s += __shfl_xor(s, 4); s += __shfl_xor(s, 8);
      float inv = 1.0f / s;
#pragma unroll
      for (int dt = 0; dt < 8; dt++)
        ob[((size_t)(q0 + m*16 + lg*4 + r)*NH + h)*128 + dt*16 + lr] =
            f2bf(O[dt][m][r] * inv);
    }
}

extern "C" void kernel_launch(void* const* d_in, const int* in_sizes, int n_in,
                              void* d_out, int out_size, void* d_ws, size_t ws_size,
                              hipStream_t stream) {
  (void)in_sizes; (void)n_in; (void)out_size; (void)ws_size;
  const float* x        = (const float*)d_in[0];
  const int*   positions= (const int*)d_in[1];
  const float* Wq       = (const float*)d_in[2];
  const float* Wk       = (const float*)d_in[3];
  const float* Wv       = (const float*)d_in[4];
  const float* Wo       = (const float*)d_in[5];
  const float* q_scale  = (const float*)d_in[6];
  const float* k_scale  = (const float*)d_in[7];
  float* out = (float*)d_out;

  char* ws = (char*)d_ws;
  u16* xb   = (u16*)ws; ws += (size_t)4096*2048*2;   // x bf16
  u16* Wt   = (u16*)ws; ws += (size_t)3072*2048*2;   // [Wq|Wk|Wv]^T bf16 [3072][2048]
  u16* Wot  = (u16*)ws; ws += (size_t)2048*2048*2;   // Wo^T bf16
  u16* qkvb = (u16*)ws; ws += (size_t)4096*3072*2;   // fused qkv bf16
  u16* qb   = (u16*)ws; ws += (size_t)4096*2048*2;   // q roped bf16 (pre-scaled)
  u16* kb   = (u16*)ws; ws += (size_t)4096*512*2;    // k roped bf16
  u16* vT   = (u16*)ws; ws += (size_t)4096*512*2;    // v^T bf16 [4][128][L]
  u16* ob   = qkvb;                                  // attn out aliases qkvb (dead)

  k_cvt<<<8192, 256, 0, stream>>>(x, xb, 2097152);
  k_transpose64<<<dim3(32,32), 256, 0, stream>>>(Wq, Wt, 2048, 2048, 0);
  k_transpose64<<<dim3(8,32),  256, 0, stream>>>(Wk, Wt, 2048, 512, 2048);
  k_transpose64<<<dim3(8,32),  256, 0, stream>>>(Wv, Wt, 2048, 512, 2560);
  k_transpose64<<<dim3(32,32), 256, 0, stream>>>(Wo, Wot, 2048, 2048, 0);
  k_gemm_bt<1><<<dim3(24,32), 256, 0, stream>>>(xb, Wt, qkvb, 4096, 3072, 2048);
  k_qknorm<<<1024, 256, 0, stream>>>(qkvb, positions, q_scale, k_scale, qb, kb);
  k_vtrans<<<dim3(64,8), 256, 0, stream>>>(qkvb, vT);
  k_attn<<<dim3(128,4), 256, 0, stream>>>(qb, kb, vT, ob);
  k_gemm_bt<0><<<dim3(16,32), 256, 0, stream>>>(ob, Wot, out, 4096, 2048, 2048);
}

// Round 4
// 288.884 us; speedup vs baseline: 1.8899x; 1.0945x over previous
//
#include <hip/hip_runtime.h>
#include <cstdint>
#include <cstddef>

typedef unsigned short u16;
typedef __attribute__((ext_vector_type(4))) float  float4v;
typedef __attribute__((ext_vector_type(4))) int    int4v;
typedef __attribute__((ext_vector_type(8))) short  short8v;
typedef __attribute__((ext_vector_type(4))) short  short4v;

#define L_SEQ 4096
#define NH 16
#define NKV 4
#define WND 1024

static __device__ __forceinline__ u16 f2bf(float f) {
  union { float f; unsigned u; } v; v.f = f;
  unsigned r = (v.u + 0x7FFFu + ((v.u >> 16) & 1u)) >> 16;  // RNE
  return (u16)r;
}
static __device__ __forceinline__ u16 f2bf_fast(float f) {   // round-half-up, 2 ops
  union { float f; unsigned u; } v; v.f = f;
  return (u16)((v.u + 0x8000u) >> 16);
}
static __device__ __forceinline__ float bf2f(u16 b) {
  union { unsigned u; float f; } v; v.u = ((unsigned)b) << 16;
  return v.f;
}

// ---------------- fp32 -> bf16 elementwise (x4 vectorized) ----------------
__global__ __launch_bounds__(256) void k_cvt(const float* __restrict__ in,
                                             u16* __restrict__ out, int n4) {
  int i = blockIdx.x * 256 + threadIdx.x;
  if (i >= n4) return;
  float4v v = ((const float4v*)in)[i];
  short4v o;
  o[0] = (short)f2bf(v[0]); o[1] = (short)f2bf(v[1]);
  o[2] = (short)f2bf(v[2]); o[3] = (short)f2bf(v[3]);
  ((short4v*)out)[i] = o;
}

// --- transpose+convert 64x64: in fp32 [K][N] -> out bf16 [(row_off+n)][K] ---
__global__ __launch_bounds__(256) void k_transpose64(const float* __restrict__ in,
                                                     u16* __restrict__ out,
                                                     int K, int N, int row_off) {
  __shared__ float tile[64][65];
  int n0 = blockIdx.x * 64, k0 = blockIdx.y * 64;
  int tx = threadIdx.x & 63, ty = threadIdx.x >> 6;
#pragma unroll
  for (int i = 0; i < 16; i++)
    tile[ty + i*4][tx] = in[(size_t)(k0 + ty + i*4)*N + n0 + tx];
  __syncthreads();
#pragma unroll
  for (int i = 0; i < 16; i++)
    out[(size_t)(row_off + n0 + ty + i*4)*K + k0 + tx] = f2bf(tile[tx][ty + i*4]);
}

// --- V extract+transpose: qkvb bf16 [L][3072] cols 2560.. -> vT bf16 [512][L] ---
__global__ __launch_bounds__(256) void k_vtrans(const u16* __restrict__ qkvb,
                                                u16* __restrict__ vT) {
  __shared__ u16 tile[64][66];
  int p0 = blockIdx.x * 64, d0 = blockIdx.y * 64;
  int tx = threadIdx.x & 63, ty = threadIdx.x >> 6;
#pragma unroll
  for (int i = 0; i < 16; i++)
    tile[ty + i*4][tx] = qkvb[(size_t)(p0 + ty + i*4)*3072 + 2560 + d0 + tx];
  __syncthreads();
#pragma unroll
  for (int i = 0; i < 16; i++)
    vT[(size_t)(d0 + ty + i*4)*L_SEQ + p0 + tx] = tile[tx][ty + i*4];
}

// ---------------- bf16 MFMA GEMM, B^T, BK=64, XOR-swizzled LDS ----------------
template<int BF16_OUT>
__global__ __launch_bounds__(256) void k_gemm_bt(const u16* __restrict__ A,
                                                 const u16* __restrict__ B,
                                                 void* __restrict__ Cv,
                                                 int M, int N, int K) {
  __shared__ alignas(16) u16 As[128*64];
  __shared__ alignas(16) u16 Bs[128*64];
  int tid = threadIdx.x;
  int lane = tid & 63, wave = tid >> 6;
  int lr = lane & 15, lg = lane >> 4;
  int m0 = blockIdx.y * 128, n0 = blockIdx.x * 128;
  int wm = (wave >> 1) * 64, wn = (wave & 1) * 64;

  float4v acc[4][4];
#pragma unroll
  for (int i = 0; i < 4; i++)
#pragma unroll
    for (int j = 0; j < 4; j++)
#pragma unroll
      for (int r = 0; r < 4; r++) acc[i][j][r] = 0.f;

  for (int kt = 0; kt < K; kt += 64) {
    __syncthreads();
#pragma unroll
    for (int it = 0; it < 4; it++) {
      int s = it*256 + tid;
      int row = s >> 3, j = s & 7;
      int col = ((j ^ (row & 7)) << 3);
      __builtin_amdgcn_global_load_lds(
          (const __attribute__((address_space(1))) void*)(A + (size_t)(m0 + row)*K + kt + col),
          (__attribute__((address_space(3))) void*)(&As[s * 8]), 16, 0, 0);
      __builtin_amdgcn_global_load_lds(
          (const __attribute__((address_space(1))) void*)(B + (size_t)(n0 + row)*K + kt + col),
          (__attribute__((address_space(3))) void*)(&Bs[s * 8]), 16, 0, 0);
    }
    __syncthreads();
#pragma unroll
    for (int half = 0; half < 2; half++) {
      short8v af[4], bf[4];
#pragma unroll
      for (int i = 0; i < 4; i++) {
        int row = wm + i*16 + lr;
        af[i] = *(const short8v*)(&As[row*64 + ((((half<<2)|lg) ^ (row & 7)) << 3)]);
      }
#pragma unroll
      for (int j = 0; j < 4; j++) {
        int row = wn + j*16 + lr;
        bf[j] = *(const short8v*)(&Bs[row*64 + ((((half<<2)|lg) ^ (row & 7)) << 3)]);
      }
#pragma unroll
      for (int i = 0; i < 4; i++)
#pragma unroll
        for (int j = 0; j < 4; j++)
          acc[i][j] = __builtin_amdgcn_mfma_f32_16x16x32_bf16(af[i], bf[j], acc[i][j], 0, 0, 0);
    }
  }
#pragma unroll
  for (int i = 0; i < 4; i++)
#pragma unroll
    for (int j = 0; j < 4; j++)
#pragma unroll
      for (int r = 0; r < 4; r++) {
        size_t idx = (size_t)(m0 + wm + i*16 + lg*4 + r)*N + (n0 + wn + j*16 + lr);
        if (BF16_OUT) ((u16*)Cv)[idx] = f2bf(acc[i][j][r]);
        else          ((float*)Cv)[idx] = acc[i][j][r];
      }
}

// ---------------- RMSNorm + RoPE for Q,K ----------------
// Q pre-scaled by HD^-0.5 * log2(e) so attention uses exp2 with no per-score mul.
__global__ __launch_bounds__(256) void k_qknorm(const u16* __restrict__ qkvb,
    const int* __restrict__ positions, const float* __restrict__ q_scale,
    const float* __restrict__ k_scale, u16* __restrict__ qb,
    u16* __restrict__ kb) {
  int p = blockIdx.x * 4 + (threadIdx.x >> 6);
  int l = threadIdx.x & 63;
  const float LOG2_BASE = 13.287712379549449f;
  float ang = (float)positions[p] * exp2f(-(float)l * (LOG2_BASE / 64.0f));
  float sn, cs; sincosf(ang, &sn, &cs);
  float qs1 = q_scale[l], qs2 = q_scale[l + 64];
  float ks1 = k_scale[l], ks2 = k_scale[l + 64];
  const u16* base = qkvb + (size_t)p * 3072;
  const float qsc = 0.12751741505539613f;  // 128^-0.5 * log2(e)
#pragma unroll
  for (int h = 0; h < 16; h++) {
    float x1 = bf2f(base[h*128 + l]), x2 = bf2f(base[h*128 + l + 64]);
    float ss = x1*x1 + x2*x2;
#pragma unroll
    for (int m = 1; m < 64; m <<= 1) ss += __shfl_xor(ss, m);
    float rinv = rsqrtf(ss * (1.0f/128.0f) + 1e-6f);
    x1 *= rinv * qs1; x2 *= rinv * qs2;
    u16* dst = qb + ((size_t)p*NH + h)*128;
    dst[l]      = f2bf((x1*cs - x2*sn) * qsc);
    dst[l + 64] = f2bf((x2*cs + x1*sn) * qsc);
  }
#pragma unroll
  for (int g = 0; g < 4; g++) {
    float x1 = bf2f(base[2048 + g*128 + l]), x2 = bf2f(base[2048 + g*128 + l + 64]);
    float ss = x1*x1 + x2*x2;
#pragma unroll
    for (int m = 1; m < 64; m <<= 1) ss += __shfl_xor(ss, m);
    float rinv = rsqrtf(ss * (1.0f/128.0f) + 1e-6f);
    x1 *= rinv * ks1; x2 *= rinv * ks2;
    u16* dst = kb + ((size_t)p*NKV + g)*128;
    dst[l]      = f2bf(x1*cs - x2*sn);
    dst[l + 64] = f2bf(x2*cs + x1*sn);
  }
}

// ---------------- flash attention v3 ----------------
// XCD-aware block decode: xcd = blockIdx&7 owns one (group, q-half) strip of 64
// consecutive q-tiles -> per-XCD K/V L2 footprint ~1.6 MB (fits 4 MB L2).
// 64-key tiles staged via global_load_lds (XOR-swizzled, conflict-free).
// Fixed-max softmax (RMSNorm bounds |S|); denominator via MFMA against ones.
__global__ __launch_bounds__(256) void k_attn(const u16* __restrict__ qb,
    const u16* __restrict__ kb, const u16* __restrict__ vT,
    u16* __restrict__ ob) {
  __shared__ alignas(16) u16 Ks[64*128];      // [key][dim], chunk c at slot c^(row&15)
  __shared__ alignas(16) u16 Vs[128*64];      // [dim][key], chunk c at slot c^(row&7)
  __shared__ alignas(16) u16 Pw[4][2][16*72]; // per-wave P transpose, pad 64->72
  int tid = threadIdx.x;
  int lane = tid & 63, wave = tid >> 6;
  int lr = lane & 15, lg = lane >> 4;
  int flat = blockIdx.x;
  int xcd = flat & 7, slot = flat >> 3;
  int gh = xcd >> 1;
  int q0 = ((xcd & 1) * 64 + slot) * 32;
  int h = gh * 4 + wave;

  short8v qf[2][4];
#pragma unroll
  for (int m = 0; m < 2; m++) {
    const u16* qrow = qb + ((size_t)(q0 + m*16 + lr)*NH + h)*128 + lg*8;
#pragma unroll
    for (int t = 0; t < 4; t++) qf[m][t] = *(const short8v*)(qrow + t*32);
  }

  const short one_bf = (short)0x3F80;
  const short8v ones = {one_bf,one_bf,one_bf,one_bf,one_bf,one_bf,one_bf,one_bf};

  float4v O[9][2];   // O[8] = P @ ones = softmax denominator
#pragma unroll
  for (int dt = 0; dt < 9; dt++)
#pragma unroll
    for (int m = 0; m < 2; m++)
#pragma unroll
      for (int r = 0; r < 4; r++) O[dt][m][r] = 0.f;

  int kstart = q0 - (WND - 1); if (kstart < 0) kstart = 0; kstart &= ~63;
  for (int kt = kstart; kt < q0 + 32; kt += 64) {
    __syncthreads();
#pragma unroll
    for (int it = 0; it < 4; it++) {
      int s = it*256 + tid;
      { int row = s >> 4, j = s & 15, col = (j ^ (row & 15)) << 3;
        __builtin_amdgcn_global_load_lds(
            (const __attribute__((address_space(1))) void*)(kb + (size_t)(kt + row)*512 + gh*128 + col),
            (__attribute__((address_space(3))) void*)(&Ks[s * 8]), 16, 0, 0); }
      { int row = s >> 3, j = s & 7, col = (j ^ (row & 7)) << 3;
        __builtin_amdgcn_global_load_lds(
            (const __attribute__((address_space(1))) void*)(vT + (size_t)(gh*128 + row)*L_SEQ + kt + col),
            (__attribute__((address_space(3))) void*)(&Vs[s * 8]), 16, 0, 0); }
    }
    __syncthreads();

    float4v S[2][4];
#pragma unroll
    for (int m = 0; m < 2; m++)
#pragma unroll
      for (int t2 = 0; t2 < 4; t2++)
#pragma unroll
        for (int r = 0; r < 4; r++) S[m][t2][r] = 0.f;
#pragma unroll
    for (int t2 = 0; t2 < 4; t2++) {
      int row = t2*16 + lr;
#pragma unroll
      for (int t = 0; t < 4; t++) {
        short8v kf = *(const short8v*)(&Ks[row*128 + (((t*4 + lg) ^ (row & 15)) << 3)]);
        S[0][t2] = __builtin_amdgcn_mfma_f32_16x16x32_bf16(qf[0][t], kf, S[0][t2], 0, 0, 0);
        S[1][t2] = __builtin_amdgcn_mfma_f32_16x16x32_bf16(qf[1][t], kf, S[1][t2], 0, 0, 0);
      }
    }

    // P = exp2(S) with masking only on boundary tiles
    bool need_mask = (kt + 64 > q0) || (kt < q0 - (WND - 32));
    if (need_mask) {
#pragma unroll
      for (int m = 0; m < 2; m++)
#pragma unroll
        for (int r = 0; r < 4; r++) {
          int pos = q0 + m*16 + lg*4 + r;
#pragma unroll
          for (int t2 = 0; t2 < 4; t2++) {
            int key = kt + t2*16 + lr;
            float p = (key > pos || key < pos - (WND - 1)) ? 0.f : exp2f(S[m][t2][r]);
            Pw[wave][m][(lg*4 + r)*72 + t2*16 + lr] = f2bf_fast(p);
          }
        }
    } else {
#pragma unroll
      for (int m = 0; m < 2; m++)
#pragma unroll
        for (int r = 0; r < 4; r++)
#pragma unroll
          for (int t2 = 0; t2 < 4; t2++)
            Pw[wave][m][(lg*4 + r)*72 + t2*16 + lr] = f2bf_fast(exp2f(S[m][t2][r]));
    }

    short8v pf[2][2];
#pragma unroll
    for (int m = 0; m < 2; m++)
#pragma unroll
      for (int sub = 0; sub < 2; sub++)
        pf[m][sub] = *(const short8v*)(&Pw[wave][m][lr*72 + sub*32 + lg*8]);

#pragma unroll
    for (int sub = 0; sub < 2; sub++)
#pragma unroll
      for (int dt = 0; dt < 8; dt++) {
        int row = dt*16 + lr;
        short8v vf = *(const short8v*)(&Vs[row*64 + (((sub*4 + lg) ^ (row & 7)) << 3)]);
        O[dt][0] = __builtin_amdgcn_mfma_f32_16x16x32_bf16(pf[0][sub], vf, O[dt][0], 0, 0, 0);
        O[dt][1] = __builtin_amdgcn_mfma_f32_16x16x32_bf16(pf[1][sub], vf, O[dt][1], 0, 0, 0);
      }
#pragma unroll
    for (int m = 0; m < 2; m++) {
      O[8][m] = __builtin_amdgcn_mfma_f32_16x16x32_bf16(pf[m][0], ones, O[8][m], 0, 0, 0);
      O[8][m] = __builtin_amdgcn_mfma_f32_16x16x32_bf16(pf[m][1], ones, O[8][m], 0, 0, 0);
    }
  }

#pragma unroll
  for (int m = 0; m < 2; m++)
#pragma unroll
    for (int r = 0; r < 4; r++) {
      float inv = 1.0f / O[8][m][r];   // denominator already lane-resident (col-broadcast)
#pragma unroll
      for (int dt = 0; dt < 8; dt++)
        ob[((size_t)(q0 + m*16 + lg*4 + r)*NH + h)*128 + dt*16 + lr] =
            f2bf(O[dt][m][r] * inv);
    }
}

extern "C" void kernel_launch(void* const* d_in, const int* in_sizes, int n_in,
                              void* d_out, int out_size, void* d_ws, size_t ws_size,
                              hipStream_t stream) {
  (void)in_sizes; (void)n_in; (void)out_size; (void)ws_size;
  const float* x        = (const float*)d_in[0];
  const int*   positions= (const int*)d_in[1];
  const float* Wq       = (const float*)d_in[2];
  const float* Wk       = (const float*)d_in[3];
  const float* Wv       = (const float*)d_in[4];
  const float* Wo       = (const float*)d_in[5];
  const float* q_scale  = (const float*)d_in[6];
  const float* k_scale  = (const float*)d_in[7];
  float* out = (float*)d_out;

  char* ws = (char*)d_ws;
  u16* xb   = (u16*)ws; ws += (size_t)4096*2048*2;
  u16* Wt   = (u16*)ws; ws += (size_t)3072*2048*2;
  u16* Wot  = (u16*)ws; ws += (size_t)2048*2048*2;
  u16* qkvb = (u16*)ws; ws += (size_t)4096*3072*2;
  u16* qb   = (u16*)ws; ws += (size_t)4096*2048*2;
  u16* kb   = (u16*)ws; ws += (size_t)4096*512*2;
  u16* vT   = (u16*)ws; ws += (size_t)4096*512*2;
  u16* ob   = qkvb;

  k_cvt<<<8192, 256, 0, stream>>>(x, xb, 2097152);
  k_transpose64<<<dim3(32,32), 256, 0, stream>>>(Wq, Wt, 2048, 2048, 0);
  k_transpose64<<<dim3(8,32),  256, 0, stream>>>(Wk, Wt, 2048, 512, 2048);
  k_transpose64<<<dim3(8,32),  256, 0, stream>>>(Wv, Wt, 2048, 512, 2560);
  k_transpose64<<<dim3(32,32), 256, 0, stream>>>(Wo, Wot, 2048, 2048, 0);
  k_gemm_bt<1><<<dim3(24,32), 256, 0, stream>>>(xb, Wt, qkvb, 4096, 3072, 2048);
  k_qknorm<<<1024, 256, 0, stream>>>(qkvb, positions, q_scale, k_scale, qb, kb);
  k_vtrans<<<dim3(64,8), 256, 0, stream>>>(qkvb, vT);
  k_attn<<<512, 256, 0, stream>>>(qb, kb, vT, ob);
  k_gemm_bt<0><<<dim3(16,32), 256, 0, stream>>>(ob, Wot, out, 4096, 2048, 2048);
}